// Round 6
// baseline (131.828 us; speedup 1.0000x reference)
//
#include <hip/hip_runtime.h>
#include <hip/hip_bf16.h>

#define N_HALF 4096
#define M_TOT  8192
#define D      256
#define TTILE  (M_TOT / 256)               // 32 row/col tiles
#define NBLK   (TTILE * (TTILE + 1) / 2)   // 528 lower-triangle blocks

typedef __attribute__((ext_vector_type(8))) short bf16x8;
typedef __attribute__((ext_vector_type(4))) float f32x4;

__device__ __forceinline__ float wave_reduce_sum(float v) {
    v += __shfl_xor(v, 1);
    v += __shfl_xor(v, 2);
    v += __shfl_xor(v, 4);
    v += __shfl_xor(v, 8);
    v += __shfl_xor(v, 16);
    v += __shfl_xor(v, 32);
    return v;
}

// Fused: normalize both rows of pair r, positive-pair dot, zero rowsum, zero out.
__global__ void k_prep(const float* __restrict__ zis, const float* __restrict__ zjs,
                       __hip_bfloat16* __restrict__ zn, float* __restrict__ rowsum,
                       float* __restrict__ pos_part, float* __restrict__ out) {
    int r = blockIdx.x;        // 0..4095
    int t = threadIdx.x;       // 0..255
    float zi = zis[(size_t)r * D + t];
    float zj = zjs[(size_t)r * D + t];
    float ssi = wave_reduce_sum(zi * zi);
    float ssj = wave_reduce_sum(zj * zj);
    float dd  = wave_reduce_sum(zi * zj);
    __shared__ float red[3][4];
    int w = t >> 6;
    if ((t & 63) == 0) { red[0][w] = ssi; red[1][w] = ssj; red[2][w] = dd; }
    __syncthreads();
    float ni = fmaxf(sqrtf(red[0][0] + red[0][1] + red[0][2] + red[0][3]), 1e-8f);
    float nj = fmaxf(sqrtf(red[1][0] + red[1][1] + red[1][2] + red[1][3]), 1e-8f);
    zn[(size_t)r * D + t]            = __float2bfloat16(zj / nj);
    zn[(size_t)(r + N_HALF) * D + t] = __float2bfloat16(zi / ni);
    if (t == 0) {
        float dot = red[2][0] + red[2][1] + red[2][2] + red[2][3];
        pos_part[r] = dot / (ni * nj) * 4.0f;   // each unordered pair 2x, /T -> *4
        rowsum[r] = 0.0f;
        rowsum[r + N_HALF] = 0.0f;
        if (r == 0) out[0] = 0.0f;
    }
}

// Symmetric-triangle k_main, BARRIER-FREE streaming version.
// Round-5 post-mortem: k_main ~30us vs ~6-8us overlapped pipe floor; the gap
// is the per-jt barrier+drain structure. zn is 4 MB = fully L2-resident per
// XCD, so LDS staging of B is pure overhead (Common-mistake #7 / m169):
// read B-fragments DIRECTLY from global into registers. No per-tile barriers;
// waves run as independent streams; L2 latency hidden by an explicit 2-deep
// register pipeline (named bA/bB arrays - rule #20, no runtime indexing) + TLP.
// LDS = 1 KB colsum only; 2 __syncthreads total per block.
// Off-diag tiles scatter exp(sim) to rowsum[i] (row-reduce, registers) AND
// rowsum[j] (col-reduce via LDS colsum, flushed once). Diag tiles computed in
// full, col-side skipped. Exact partition of sim (ex-diagonal).
__global__ __launch_bounds__(256)
void k_main(const __hip_bfloat16* __restrict__ znh, float* __restrict__ rowsum) {
    __shared__ float colsum[256];              // 1 KB - only LDS in kernel
    const ushort* zn = reinterpret_cast<const ushort*>(znh);
    int tid  = threadIdx.x;
    int wave = tid >> 6;
    int lane = tid & 63;
    int q    = lane >> 4;   // quad
    int li   = lane & 15;

    // triangle decode: b -> (bi, bj), bi <= bj, b = bj*(bj+1)/2 + bi
    int b = blockIdx.x;
    int t = (int)((sqrtf(8.0f * (float)b + 1.0f) - 1.0f) * 0.5f);
    while ((t + 1) * (t + 2) / 2 <= b) ++t;
    while (t * (t + 1) / 2 > b) --t;
    int bj = t;
    int bi = b - t * (t + 1) / 2;
    bool diag = (bi == bj);

    int i_base = bi * 256 + wave * 64;
    int j0     = bj * 256;

    // A fragment (16x16x32 bf16): A[m][k], m = lane&15, k = quad*8 + j
    bf16x8 afrag[4][8];
#pragma unroll
    for (int it = 0; it < 4; ++it) {
        const ushort* ap = zn + (((size_t)(i_base + it * 16 + li)) << 8) + q * 8;
#pragma unroll
        for (int kt = 0; kt < 8; ++kt)
            afrag[it][kt] = *reinterpret_cast<const bf16x8*>(ap + kt * 32);
    }

    float part[4][4];   // [i_tile][reg-row]
#pragma unroll
    for (int it = 0; it < 4; ++it)
#pragma unroll
        for (int r = 0; r < 4; ++r) part[it][r] = 0.0f;

    colsum[tid] = 0.0f;
    __syncthreads();

    // Per-lane B base: row j0 + li, col q*8. B-frag (j16, kt) at
    // + j16*16*256 + kt*32 (ushort units). 16 j16-tiles cover 256 j-cols.
    const ushort* bp = zn + (((size_t)(j0 + li)) << 8) + q * 8;

#define LOADB(dst, J16)                                                          \
    {                                                                            \
        _Pragma("unroll")                                                        \
        for (int kt = 0; kt < 8; ++kt)                                           \
            dst[kt] = *reinterpret_cast<const bf16x8*>(bp + (J16) * 4096 + kt * 32); \
    }

#define COMPUTE(bX, J16)                                                         \
    {                                                                            \
        f32x4 acc[4] = {{0,0,0,0},{0,0,0,0},{0,0,0,0},{0,0,0,0}};                \
        _Pragma("unroll")                                                        \
        for (int kt = 0; kt < 8; ++kt)                                           \
            _Pragma("unroll")                                                    \
            for (int it = 0; it < 4; ++it)                                       \
                acc[it] = __builtin_amdgcn_mfma_f32_16x16x32_bf16(               \
                    afrag[it][kt], bX[kt], acc[it], 0, 0, 0);                    \
        float cs = 0.0f;                                                         \
        _Pragma("unroll")                                                        \
        for (int it = 0; it < 4; ++it)                                           \
            _Pragma("unroll")                                                    \
            for (int r = 0; r < 4; ++r) {                                        \
                float e = __expf(acc[it][r] * 2.0f - 2.0f);                      \
                part[it][r] += e;                                                \
                cs += e;                                                         \
            }                                                                    \
        cs += __shfl_xor(cs, 16);                                                \
        cs += __shfl_xor(cs, 32);                                                \
        if (q == 0) atomicAdd(&colsum[(J16) * 16 + li], cs);                     \
    }

    // 2-deep software pipeline over 16 j16-tiles (named arrays, static indexing)
    bf16x8 bA[8], bB[8];
    LOADB(bA, 0)
#pragma unroll
    for (int j16 = 0; j16 < 16; j16 += 2) {
        LOADB(bB, j16 + 1)
        COMPUTE(bA, j16)
        if (j16 + 2 < 16) LOADB(bA, j16 + 2)
        COMPUTE(bB, j16 + 1)
    }
#undef LOADB
#undef COMPUTE

    // Row-side: reduce across the 16 lanes holding different j-cols of the same rows.
#pragma unroll
    for (int it = 0; it < 4; ++it)
#pragma unroll
        for (int r = 0; r < 4; ++r) {
            float v = part[it][r];
            v += __shfl_xor(v, 1);
            v += __shfl_xor(v, 2);
            v += __shfl_xor(v, 4);
            v += __shfl_xor(v, 8);
            if (li == 0) atomicAdd(&rowsum[i_base + it * 16 + q * 4 + r], v);
        }

    // Col-side: transpose contribution rowsum[j] += sum_i exp(sim_ij).
    __syncthreads();   // all colsum atomics visible
    if (!diag) atomicAdd(&rowsum[j0 + tid], colsum[tid]);
}

// lse_i = 2 + log(rowsum_i - 1); loss = (sum lse - sum pos)/M.
// 32 blocks; per-block partial -> atomicAdd into pre-zeroed out[0].
__global__ void k_final(const float* __restrict__ rowsum, const float* __restrict__ pos_part,
                        float* __restrict__ out) {
    int idx = blockIdx.x * 256 + threadIdx.x;   // 0..8191
    float acc  = 2.0f + __logf(rowsum[idx] - 1.0f);
    float pacc = (idx < N_HALF) ? pos_part[idx] : 0.0f;
    acc  = wave_reduce_sum(acc);
    pacc = wave_reduce_sum(pacc);
    __shared__ float wsum[4], psum[4];
    int t = threadIdx.x;
    if ((t & 63) == 0) { wsum[t >> 6] = acc; psum[t >> 6] = pacc; }
    __syncthreads();
    if (t == 0) {
        float tot = wsum[0] + wsum[1] + wsum[2] + wsum[3]
                  - (psum[0] + psum[1] + psum[2] + psum[3]);
        atomicAdd(out, tot / (float)M_TOT);
    }
}

extern "C" void kernel_launch(void* const* d_in, const int* in_sizes, int n_in,
                              void* d_out, int out_size, void* d_ws, size_t ws_size,
                              hipStream_t stream) {
    const float* zis = (const float*)d_in[0];
    const float* zjs = (const float*)d_in[1];
    char* ws = (char*)d_ws;
    __hip_bfloat16* zn = (__hip_bfloat16*)ws;                         // 4 MB
    float* rowsum   = (float*)(ws + (size_t)M_TOT * D * 2);           // 32 KB
    float* pos_part = rowsum + M_TOT;                                 // 16 KB
    float* out = (float*)d_out;

    k_prep<<<N_HALF, 256, 0, stream>>>(zis, zjs, zn, rowsum, pos_part, out);
    k_main<<<NBLK, 256, 0, stream>>>(zn, rowsum);
    k_final<<<M_TOT / 256, 256, 0, stream>>>(rowsum, pos_part, out);
}